// Round 4
// baseline (426.922 us; speedup 1.0000x reference)
//
#include <hip/hip_runtime.h>
#include <math.h>

#define S_LEN 1024
#define D_MOD 512
#define NH 8
#define DK 64
#define NB 8

typedef __attribute__((ext_vector_type(8))) short short8;   // 8 bf16 in 4 VGPRs
typedef __attribute__((ext_vector_type(4))) float floatx4;  // MFMA accumulator

union U8 { ushort u[8]; short8 v; };

__device__ __forceinline__ ushort f2bf(float x) {
  unsigned u = __float_as_uint(x);
  unsigned r = (u + 0x7fffu + ((u >> 16) & 1u)) >> 16;  // RNE
  return (ushort)r;
}

// ---------------------------------------------------------------------------
// fp32 -> bf16 convert for q,k,v in one launch (blockIdx.y selects tensor)
// ---------------------------------------------------------------------------
__global__ __launch_bounds__(256) void cvt3_kern(
    const float* __restrict__ q, const float* __restrict__ k,
    const float* __restrict__ v, ushort* __restrict__ qo,
    ushort* __restrict__ ko, ushort* __restrict__ vo)
{
  const int z = blockIdx.y;
  const float* src = (z == 0) ? q : (z == 1) ? k : v;
  ushort* dst = (z == 0) ? qo : (z == 1) ? ko : vo;
  const int i = blockIdx.x * 256 + threadIdx.x;
  const float4 a = *((const float4*)src + i * 2);
  const float4 b = *((const float4*)src + i * 2 + 1);
  U8 o;
  o.u[0] = f2bf(a.x); o.u[1] = f2bf(a.y); o.u[2] = f2bf(a.z); o.u[3] = f2bf(a.w);
  o.u[4] = f2bf(b.x); o.u[5] = f2bf(b.y); o.u[6] = f2bf(b.z); o.u[7] = f2bf(b.w);
  *(short8*)(dst + (size_t)i * 8) = o.v;
}

// ---------------------------------------------------------------------------
// Weight transpose+convert: W fp32 [512(k),512(n)] -> Wt bf16 [512(n),512(k)]
// blockIdx.z selects Wq/Wv/Wo.
// ---------------------------------------------------------------------------
__global__ __launch_bounds__(256) void wtrans3_kern(
    const float* __restrict__ W0, const float* __restrict__ W1,
    const float* __restrict__ W2, ushort* __restrict__ T0,
    ushort* __restrict__ T1, ushort* __restrict__ T2)
{
  const int z = blockIdx.z;
  const float* W = (z == 0) ? W0 : (z == 1) ? W1 : W2;
  ushort* Wt = (z == 0) ? T0 : (z == 1) ? T1 : T2;
  __shared__ __align__(16) ushort tile[64][72];
  const int t = threadIdx.x;
  const int n0 = blockIdx.x * 64;
  const int k0 = blockIdx.y * 64;
  {
    const int r = t >> 2;
    const int c0 = (t & 3) * 16;
    const float* p = &W[(size_t)(k0 + r) * 512 + n0 + c0];
#pragma unroll
    for (int j = 0; j < 16; ++j) tile[r][c0 + j] = f2bf(p[j]);
  }
  __syncthreads();
  {
    const int c = t >> 2;
    const int kg = (t & 3) * 16;
    U8 lo, hi;
#pragma unroll
    for (int j = 0; j < 8; ++j) lo.u[j] = tile[kg + j][c];
#pragma unroll
    for (int j = 0; j < 8; ++j) hi.u[j] = tile[kg + 8 + j][c];
    ushort* q = &Wt[(size_t)(n0 + c) * 512 + k0 + kg];
    *(short8*)q = lo.v;
    *(short8*)(q + 8) = hi.v;
  }
}

// ---------------------------------------------------------------------------
// state_mask int32 [B,S,S] -> bit words u64 [B,S,S/64] (bit k = mask!=0)
// ---------------------------------------------------------------------------
__global__ __launch_bounds__(256) void maskbits_kern(
    const int* __restrict__ smask, unsigned long long* __restrict__ mb)
{
  const int row = blockIdx.x * 4 + (threadIdx.x >> 6);
  const int lane = threadIdx.x & 63;
  const int* p = smask + (size_t)row * S_LEN;
  unsigned long long mine = 0;
#pragma unroll
  for (int r = 0; r < 16; ++r) {
    int m = p[r * 64 + lane];
    unsigned long long w = __ballot(m != 0);
    if (lane == r) mine = w;
  }
  if (lane < 16) mb[(size_t)row * 16 + lane] = mine;
}

// ---------------------------------------------------------------------------
// Batched bf16 MFMA GEMM for Q/K/V projections (blockIdx.z selects).
// Block tile 64m x 64n, 4 waves each 16m x 64n (1 A-frag : 4 B-frags : 4 MFMA).
// Grid (128, 8, 3) = 3072 blocks -> high wave-parallelism (latency-bound fix).
// Out: bf16 row-major [M,512].
// ---------------------------------------------------------------------------
__global__ __launch_bounds__(256) void gemm_qkv_kern(
    const ushort* __restrict__ qr, const ushort* __restrict__ kr,
    const ushort* __restrict__ vr, const ushort* __restrict__ Wqt,
    const ushort* __restrict__ Wvt, const float* __restrict__ bq,
    const float* __restrict__ bv, ushort* __restrict__ Qo,
    ushort* __restrict__ Ko, ushort* __restrict__ Vo)
{
  const int z = blockIdx.z;
  const ushort* A = (z == 0) ? qr : (z == 1) ? kr : vr;
  const ushort* Wt = (z == 2) ? Wvt : Wqt;
  const float* bias = (z == 2) ? bv : bq;
  ushort* C = (z == 0) ? Qo : (z == 1) ? Ko : Vo;

  const int t = threadIdx.x;
  const int w = t >> 6;
  const int lane = t & 63;
  const int quad = lane >> 4;
  const int i16 = lane & 15;
  const int mbase = blockIdx.x * 64 + w * 16;
  const int nbase = blockIdx.y * 64;

  floatx4 acc[4];
#pragma unroll
  for (int ni = 0; ni < 4; ++ni) acc[ni] = (floatx4)(0.f);

  const ushort* Ap = A + (size_t)(mbase + i16) * 512 + quad * 8;
  const ushort* Bp = Wt + (size_t)(nbase + i16) * 512 + quad * 8;

#pragma unroll 4
  for (int k0 = 0; k0 < 512; k0 += 32) {
    short8 af = *(const short8*)(Ap + k0);
    short8 bf[4];
#pragma unroll
    for (int ni = 0; ni < 4; ++ni)
      bf[ni] = *(const short8*)(Bp + (size_t)ni * 16 * 512 + k0);
#pragma unroll
    for (int ni = 0; ni < 4; ++ni)
      acc[ni] = __builtin_amdgcn_mfma_f32_16x16x32_bf16(af, bf[ni], acc[ni], 0, 0, 0);
  }

  float bv4[4];
#pragma unroll
  for (int ni = 0; ni < 4; ++ni) bv4[ni] = bias[nbase + ni * 16 + i16];
#pragma unroll
  for (int ni = 0; ni < 4; ++ni)
#pragma unroll
    for (int r = 0; r < 4; ++r) {
      const int m = mbase + quad * 4 + r;
      const int n = nbase + ni * 16 + i16;
      C[(size_t)m * 512 + n] = f2bf(acc[ni][r] + bv4[ni]);
    }
}

// ---------------------------------------------------------------------------
// Output GEMM: X = Obf @ Wot^T + bo + R (fp32 out). Same structure.
// ---------------------------------------------------------------------------
__global__ __launch_bounds__(256) void gemm_out_kern(
    const ushort* __restrict__ A, const ushort* __restrict__ Wt,
    const float* __restrict__ bias, const float* __restrict__ R,
    float* __restrict__ X)
{
  const int t = threadIdx.x;
  const int w = t >> 6;
  const int lane = t & 63;
  const int quad = lane >> 4;
  const int i16 = lane & 15;
  const int mbase = blockIdx.x * 64 + w * 16;
  const int nbase = blockIdx.y * 64;

  floatx4 acc[4];
#pragma unroll
  for (int ni = 0; ni < 4; ++ni) acc[ni] = (floatx4)(0.f);

  const ushort* Ap = A + (size_t)(mbase + i16) * 512 + quad * 8;
  const ushort* Bp = Wt + (size_t)(nbase + i16) * 512 + quad * 8;

#pragma unroll 4
  for (int k0 = 0; k0 < 512; k0 += 32) {
    short8 af = *(const short8*)(Ap + k0);
    short8 bf[4];
#pragma unroll
    for (int ni = 0; ni < 4; ++ni)
      bf[ni] = *(const short8*)(Bp + (size_t)ni * 16 * 512 + k0);
#pragma unroll
    for (int ni = 0; ni < 4; ++ni)
      acc[ni] = __builtin_amdgcn_mfma_f32_16x16x32_bf16(af, bf[ni], acc[ni], 0, 0, 0);
  }

  float bv4[4];
#pragma unroll
  for (int ni = 0; ni < 4; ++ni) bv4[ni] = bias[nbase + ni * 16 + i16];
#pragma unroll
  for (int ni = 0; ni < 4; ++ni)
#pragma unroll
    for (int r = 0; r < 4; ++r) {
      const int m = mbase + quad * 4 + r;
      const int n = nbase + ni * 16 + i16;
      X[(size_t)m * 512 + n] = acc[ni][r] + bv4[ni] + R[(size_t)m * 512 + n];
    }
}

// ---------------------------------------------------------------------------
// Transpose V bf16 row-major [B,S,512] -> Vt [B,H,64,S] bf16
// ---------------------------------------------------------------------------
__global__ __launch_bounds__(256) void vtrans_kern(
    const ushort* __restrict__ V, ushort* __restrict__ Vt)
{
  __shared__ __align__(16) ushort tile[64][72];
  const int t = threadIdx.x;
  const int bh = blockIdx.y;
  const int b = bh >> 3;
  const int h = bh & 7;
  const int s0 = blockIdx.x * 64;
  {
    const int r = t >> 2, c0 = (t & 3) * 16;
    const ushort* p = V + ((size_t)b * S_LEN + s0 + r) * D_MOD + h * DK + c0;
    *(short8*)&tile[r][c0] = *(const short8*)p;
    *(short8*)&tile[r][c0 + 8] = *(const short8*)(p + 8);
  }
  __syncthreads();
  {
    const int c = t >> 2, sg = (t & 3) * 16;
    U8 lo, hi;
#pragma unroll
    for (int j = 0; j < 8; ++j) lo.u[j] = tile[sg + j][c];
#pragma unroll
    for (int j = 0; j < 8; ++j) hi.u[j] = tile[sg + 8 + j][c];
    ushort* q = Vt + ((size_t)bh * DK + c) * S_LEN + s0 + sg;
    *(short8*)q = lo.v;
    *(short8*)(q + 8) = hi.v;
  }
}

// ---------------------------------------------------------------------------
// Split-K MFMA dual-score causal attention with fixed-max softmax.
// Fixed max => partial (O,l) over disjoint k-ranges merge by ADDITION.
// Grid (32, 64): block = 4 waves. Waves {0,1} -> qtile j (16 rows),
// waves {2,3} -> qtile 63-j (coarse balance). Within a pair, wave parity ph
// takes k-tiles kt = ph, ph+2, ... Merge via LDS + one barrier.
// ---------------------------------------------------------------------------
__global__ __launch_bounds__(256) void attn_mfma_kern(
    const ushort* __restrict__ Qb, const ushort* __restrict__ Kb,
    const ushort* __restrict__ Vt, const ushort* __restrict__ qraw,
    const ushort* __restrict__ kraw,
    const unsigned long long* __restrict__ mbits,
    const float* __restrict__ gammas, ushort* __restrict__ Obf)
{
  __shared__ __align__(16) ushort Plds[4][16][72];
  __shared__ float Ostage[2][4][16][17];
  __shared__ float Lstage[2][16][17];

  const int t = threadIdx.x;
  const int w = t >> 6;
  const int lane = t & 63;
  const int quad = lane >> 4;
  const int i16 = lane & 15;
  const int bh = blockIdx.y;
  const int b = bh >> 3;
  const int h = bh & 7;
  const int j = blockIdx.x;           // 0..31
  const int pi = w >> 1;              // pair index
  const int ph = w & 1;               // k-parity
  const int qt = (pi == 0) ? j : 63 - j;
  const int qbase = qt * 16;

  const float gam = gammas[h];
  float te = __expf(-log1pf(__expf(gam)));
  te = fminf(fmaxf(te, 1e-5f), 1e5f);
  const float sscale = te * 0.044194173824159216f;  // te / sqrt(512)

  // Q fragments (proj + raw), held across the k-loop
  short8 Qp[2], Qr[2];
  {
    const ushort* qp = Qb + ((size_t)b * S_LEN + qbase + i16) * D_MOD + h * DK + quad * 8;
    const ushort* qq = qraw + ((size_t)b * S_LEN + qbase + i16) * D_MOD + h * DK + quad * 8;
#pragma unroll
    for (int s = 0; s < 2; ++s) {
      Qp[s] = *(const short8*)(qp + s * 32);
      Qr[s] = *(const short8*)(qq + s * 32);
    }
  }

  floatx4 Oacc[4];
#pragma unroll
  for (int t4 = 0; t4 < 4; ++t4) Oacc[t4] = (floatx4)(0.f);
  float l_run[4] = {0.f, 0.f, 0.f, 0.f};

  const int it = (qbase + 15) / 64 + 1;   // number of 64-wide k-tiles
  for (int kt = ph; kt < it; kt += 2) {
    const int k0 = kt * 64;

    // mask bit-words for my 4 rows
    unsigned long long mw[4];
#pragma unroll
    for (int r = 0; r < 4; ++r)
      mw[r] = mbits[((size_t)b * S_LEN + qbase + quad * 4 + r) * 16 + kt];

    // scores: 16 MFMAs
    floatx4 accp[4], accr[4];
#pragma unroll
    for (int t4 = 0; t4 < 4; ++t4) { accp[t4] = (floatx4)(0.f); accr[t4] = (floatx4)(0.f); }
#pragma unroll
    for (int s = 0; s < 2; ++s) {
      const ushort* kpb = Kb + ((size_t)b * S_LEN + k0 + i16) * D_MOD + h * DK + s * 32 + quad * 8;
      const ushort* krb = kraw + ((size_t)b * S_LEN + k0 + i16) * D_MOD + h * DK + s * 32 + quad * 8;
      short8 kp[4], kr8[4];
#pragma unroll
      for (int t4 = 0; t4 < 4; ++t4) kp[t4] = *(const short8*)(kpb + (size_t)t4 * 16 * D_MOD);
#pragma unroll
      for (int t4 = 0; t4 < 4; ++t4) kr8[t4] = *(const short8*)(krb + (size_t)t4 * 16 * D_MOD);
#pragma unroll
      for (int t4 = 0; t4 < 4; ++t4)
        accp[t4] = __builtin_amdgcn_mfma_f32_16x16x32_bf16(Qp[s], kp[t4], accp[t4], 0, 0, 0);
#pragma unroll
      for (int t4 = 0; t4 < 4; ++t4)
        accr[t4] = __builtin_amdgcn_mfma_f32_16x16x32_bf16(Qr[s], kr8[t4], accr[t4], 0, 0, 0);
    }

    // combine + exp (fixed max), P -> LDS bf16
#pragma unroll
    for (int r = 0; r < 4; ++r) {
      const int qg = qbase + quad * 4 + r;
#pragma unroll
      for (int t4 = 0; t4 < 4; ++t4) {
        const int kg = k0 + t4 * 16 + i16;
        const float bitf = ((mw[r] >> (t4 * 16 + i16)) & 1ULL) ? sscale : 0.f;
        const float sv = accp[t4][r] * 0.125f + accr[t4][r] * bitf;
        const float p = (kg < qg) ? __expf(sv) : 0.f;
        l_run[r] += p;
        Plds[w][quad * 4 + r][t4 * 16 + i16] = f2bf(p);
      }
    }

    // PV: 8 MFMAs (A = P from LDS, B^T = Vt rows)
#pragma unroll
    for (int s = 0; s < 2; ++s) {
      short8 a = *(const short8*)&Plds[w][i16][s * 32 + quad * 8];
      const ushort* vb = Vt + ((size_t)bh * DK + i16) * S_LEN + k0 + s * 32 + quad * 8;
#pragma unroll
      for (int t4 = 0; t4 < 4; ++t4) {
        short8 bfv = *(const short8*)(vb + (size_t)t4 * 16 * S_LEN);
        Oacc[t4] = __builtin_amdgcn_mfma_f32_16x16x32_bf16(a, bfv, Oacc[t4], 0, 0, 0);
      }
    }
  }

  // ---- split-k merge: ph=1 publishes partials; ph=0 adds and writes ----
  if (ph == 1) {
#pragma unroll
    for (int r = 0; r < 4; ++r) {
      Lstage[pi][quad * 4 + r][i16] = l_run[r];
#pragma unroll
      for (int t4 = 0; t4 < 4; ++t4)
        Ostage[pi][t4][quad * 4 + r][i16] = Oacc[t4][r];
    }
  }
  __syncthreads();
  if (ph == 0) {
#pragma unroll
    for (int r = 0; r < 4; ++r) {
      l_run[r] += Lstage[pi][quad * 4 + r][i16];
#pragma unroll
      for (int t4 = 0; t4 < 4; ++t4)
        Oacc[t4][r] += Ostage[pi][t4][quad * 4 + r][i16];
    }
#pragma unroll
    for (int r = 0; r < 4; ++r) {
      float l = l_run[r];
#pragma unroll
      for (int off = 1; off < 16; off <<= 1) l += __shfl_xor(l, off);
      const float inv = (l > 0.f) ? 1.f / l : 0.f;
      ushort* orow = Obf + ((size_t)b * S_LEN + qbase + quad * 4 + r) * D_MOD + h * DK;
#pragma unroll
      for (int t4 = 0; t4 < 4; ++t4)
        orow[t4 * 16 + i16] = f2bf(Oacc[t4][r] * inv);
    }
  }
}

// ---------------------------------------------------------------------------
// LayerNorm over D=512, one wave per row.
// ---------------------------------------------------------------------------
__global__ __launch_bounds__(256) void ln_kern(
    const float* __restrict__ X, const float* __restrict__ gw,
    const float* __restrict__ bw, float* __restrict__ out)
{
  const int row = blockIdx.x * 4 + (threadIdx.x >> 6);
  const int lane = threadIdx.x & 63;
  const int c = lane * 8;
  const float* xp = &X[(size_t)row * D_MOD + c];
  const float4 x0 = *(const float4*)xp;
  const float4 x1 = *(const float4*)(xp + 4);
  float xv[8] = {x0.x, x0.y, x0.z, x0.w, x1.x, x1.y, x1.z, x1.w};
  float sum = 0.f;
#pragma unroll
  for (int u = 0; u < 8; ++u) sum += xv[u];
#pragma unroll
  for (int off = 1; off < 64; off <<= 1) sum += __shfl_xor(sum, off, 64);
  const float mu = sum * (1.f / 512.f);
  float ss = 0.f;
#pragma unroll
  for (int u = 0; u < 8; ++u) { xv[u] -= mu; ss += xv[u] * xv[u]; }
#pragma unroll
  for (int off = 1; off < 64; off <<= 1) ss += __shfl_xor(ss, off, 64);
  const float rstd = rsqrtf(ss * (1.f / 512.f) + 1e-5f);
  const float4 g0 = *(const float4*)&gw[c];
  const float4 g1 = *(const float4*)&gw[c + 4];
  const float4 b0 = *(const float4*)&bw[c];
  const float4 b1 = *(const float4*)&bw[c + 4];
  float* op = &out[(size_t)row * D_MOD + c];
  *(float4*)op = make_float4(xv[0] * rstd * g0.x + b0.x,
                             xv[1] * rstd * g0.y + b0.y,
                             xv[2] * rstd * g0.z + b0.z,
                             xv[3] * rstd * g0.w + b0.w);
  *(float4*)(op + 4) = make_float4(xv[4] * rstd * g1.x + b1.x,
                                   xv[5] * rstd * g1.y + b1.y,
                                   xv[6] * rstd * g1.z + b1.z,
                                   xv[7] * rstd * g1.w + b1.w);
}

// ---------------------------------------------------------------------------
extern "C" void kernel_launch(void* const* d_in, const int* in_sizes, int n_in,
                              void* d_out, int out_size, void* d_ws, size_t ws_size,
                              hipStream_t stream)
{
  const float* q_in  = (const float*)d_in[0];
  const float* k_in  = (const float*)d_in[1];
  const float* v_in  = (const float*)d_in[2];
  const int*   smask = (const int*)d_in[3];
  const float* Wq = (const float*)d_in[4];
  const float* bq = (const float*)d_in[5];
  const float* Wv = (const float*)d_in[6];
  const float* bv = (const float*)d_in[7];
  const float* Wo = (const float*)d_in[8];
  const float* bo = (const float*)d_in[9];
  const float* gammas = (const float*)d_in[10];
  const float* ln_g = (const float*)d_in[11];
  const float* ln_b = (const float*)d_in[12];
  float* out = (float*)d_out;

  char* ws = (char*)d_ws;
  const size_t BF = (size_t)NB * S_LEN * D_MOD * sizeof(ushort);  // 8 MiB
  ushort* qr  = (ushort*)(ws);                 // [0,8M)
  ushort* kr  = (ushort*)(ws + BF);            // [8M,16M)
  ushort* vr  = (ushort*)(ws + 2 * BF);        // [16M,24M); Vt overlays later
  ushort* Vt  = (ushort*)(ws + 2 * BF);
  ushort* Qbf = (ushort*)(ws + 3 * BF);        // [24M,32M)
  ushort* Kbf = (ushort*)(ws + 4 * BF);        // [32M,40M)
  ushort* Vbf = (ushort*)(ws + 5 * BF);        // [40M,48M); Obf overlays later
  ushort* Obf = (ushort*)(ws + 5 * BF);
  unsigned long long* mbits = (unsigned long long*)(ws + 6 * BF);      // 1 MiB
  ushort* Wqt = (ushort*)(ws + 6 * BF + (1 << 20));                    // 512 KiB
  ushort* Wvt = Wqt + 512 * 512;
  ushort* Wot = Wvt + 512 * 512;
  float*  X   = (float*)ws;                    // overlays qr+kr (dead by then)

  const dim3 tb(256);

  cvt3_kern<<<dim3(2048, 3), tb, 0, stream>>>(q_in, k_in, v_in, qr, kr, vr);
  wtrans3_kern<<<dim3(8, 8, 3), tb, 0, stream>>>(Wq, Wv, Wo, Wqt, Wvt, Wot);
  maskbits_kern<<<dim3(2048), tb, 0, stream>>>(smask, mbits);

  gemm_qkv_kern<<<dim3(128, 8, 3), tb, 0, stream>>>(qr, kr, vr, Wqt, Wvt,
                                                    bq, bv, Qbf, Kbf, Vbf);

  vtrans_kern<<<dim3(16, 64), tb, 0, stream>>>(Vbf, Vt);

  attn_mfma_kern<<<dim3(32, 64), tb, 0, stream>>>(Qbf, Kbf, Vt, qr, kr, mbits,
                                                  gammas, Obf);

  gemm_out_kern<<<dim3(128, 8), tb, 0, stream>>>(Obf, Wot, bo, q_in, X);
  ln_kern<<<2048, tb, 0, stream>>>(X, ln_g, ln_b, out);
}

// Round 5
// 316.234 us; speedup vs baseline: 1.3500x; 1.3500x over previous
//
#include <hip/hip_runtime.h>
#include <math.h>

#define S_LEN 1024
#define D_MOD 512
#define NH 8
#define DK 64
#define NB 8

typedef __attribute__((ext_vector_type(8))) short short8;   // 8 bf16 in 4 VGPRs
typedef __attribute__((ext_vector_type(4))) float floatx4;  // MFMA accumulator

union U8 { ushort u[8]; short8 v; };

__device__ __forceinline__ ushort f2bf(float x) {
  unsigned u = __float_as_uint(x);
  unsigned r = (u + 0x7fffu + ((u >> 16) & 1u)) >> 16;  // RNE
  return (ushort)r;
}

// ---------------------------------------------------------------------------
// fp32 -> bf16 convert for q,k,v in one launch (blockIdx.y selects tensor)
// ---------------------------------------------------------------------------
__global__ __launch_bounds__(256) void cvt3_kern(
    const float* __restrict__ q, const float* __restrict__ k,
    const float* __restrict__ v, ushort* __restrict__ qo,
    ushort* __restrict__ ko, ushort* __restrict__ vo)
{
  const int z = blockIdx.y;
  const float* src = (z == 0) ? q : (z == 1) ? k : v;
  ushort* dst = (z == 0) ? qo : (z == 1) ? ko : vo;
  const int i = blockIdx.x * 256 + threadIdx.x;
  const float4 a = *((const float4*)src + i * 2);
  const float4 b = *((const float4*)src + i * 2 + 1);
  U8 o;
  o.u[0] = f2bf(a.x); o.u[1] = f2bf(a.y); o.u[2] = f2bf(a.z); o.u[3] = f2bf(a.w);
  o.u[4] = f2bf(b.x); o.u[5] = f2bf(b.y); o.u[6] = f2bf(b.z); o.u[7] = f2bf(b.w);
  *(short8*)(dst + (size_t)i * 8) = o.v;
}

// ---------------------------------------------------------------------------
// Weight transpose+convert: W fp32 [512(k),512(n)] -> Wt bf16 [512(n),512(k)]
// ---------------------------------------------------------------------------
__global__ __launch_bounds__(256) void wtrans3_kern(
    const float* __restrict__ W0, const float* __restrict__ W1,
    const float* __restrict__ W2, ushort* __restrict__ T0,
    ushort* __restrict__ T1, ushort* __restrict__ T2)
{
  const int z = blockIdx.z;
  const float* W = (z == 0) ? W0 : (z == 1) ? W1 : W2;
  ushort* Wt = (z == 0) ? T0 : (z == 1) ? T1 : T2;
  __shared__ __align__(16) ushort tile[64][72];
  const int t = threadIdx.x;
  const int n0 = blockIdx.x * 64;
  const int k0 = blockIdx.y * 64;
  {
    const int r = t >> 2;
    const int c0 = (t & 3) * 16;
    const float* p = &W[(size_t)(k0 + r) * 512 + n0 + c0];
#pragma unroll
    for (int j = 0; j < 16; ++j) tile[r][c0 + j] = f2bf(p[j]);
  }
  __syncthreads();
  {
    const int c = t >> 2;
    const int kg = (t & 3) * 16;
    U8 lo, hi;
#pragma unroll
    for (int j = 0; j < 8; ++j) lo.u[j] = tile[kg + j][c];
#pragma unroll
    for (int j = 0; j < 8; ++j) hi.u[j] = tile[kg + 8 + j][c];
    ushort* q = &Wt[(size_t)(n0 + c) * 512 + k0 + kg];
    *(short8*)q = lo.v;
    *(short8*)(q + 8) = hi.v;
  }
}

// ---------------------------------------------------------------------------
// state_mask int32 [B,S,S] -> bit words u64 [B,S,S/64] (bit k = mask!=0)
// ---------------------------------------------------------------------------
__global__ __launch_bounds__(256) void maskbits_kern(
    const int* __restrict__ smask, unsigned long long* __restrict__ mb)
{
  const int row = blockIdx.x * 4 + (threadIdx.x >> 6);
  const int lane = threadIdx.x & 63;
  const int* p = smask + (size_t)row * S_LEN;
  unsigned long long mine = 0;
#pragma unroll
  for (int r = 0; r < 16; ++r) {
    int m = p[r * 64 + lane];
    unsigned long long w = __ballot(m != 0);
    if (lane == r) mine = w;
  }
  if (lane < 16) mb[(size_t)row * 16 + lane] = mine;
}

// ---------------------------------------------------------------------------
// Batched bf16 MFMA GEMM for Q/K/V projections (blockIdx.z selects).
// R3-proven tile: block 128m x 64n, wave 32m x 64n (2 A + 4 B : 8 MFMA).
// z=0/1: bf16 row-major out. z=2: write Vt [B,H,64,S] DIRECTLY (fuses vtrans;
// lane holds 4 consecutive s per acc reg -> 8B ushort4 stores).
// ---------------------------------------------------------------------------
__global__ __launch_bounds__(256) void gemm_qkv_kern(
    const ushort* __restrict__ qr, const ushort* __restrict__ kr,
    const ushort* __restrict__ vr, const ushort* __restrict__ Wqt,
    const ushort* __restrict__ Wvt, const float* __restrict__ bq,
    const float* __restrict__ bv, ushort* __restrict__ Qo,
    ushort* __restrict__ Ko, ushort* __restrict__ VtO)
{
  const int z = blockIdx.z;
  const ushort* A = (z == 0) ? qr : (z == 1) ? kr : vr;
  const ushort* Wt = (z == 2) ? Wvt : Wqt;
  const float* bias = (z == 2) ? bv : bq;

  const int t = threadIdx.x;
  const int w = t >> 6;
  const int lane = t & 63;
  const int quad = lane >> 4;
  const int i16 = lane & 15;
  const int mbase = blockIdx.x * 128 + w * 32;
  const int nbase = blockIdx.y * 64;

  floatx4 acc[2][4];
#pragma unroll
  for (int mi = 0; mi < 2; ++mi)
#pragma unroll
    for (int ni = 0; ni < 4; ++ni) acc[mi][ni] = (floatx4)(0.f);

  const ushort* Ap = A + (size_t)(mbase + i16) * 512 + quad * 8;
  const ushort* Bp = Wt + (size_t)(nbase + i16) * 512 + quad * 8;

#pragma unroll 4
  for (int k0 = 0; k0 < 512; k0 += 32) {
    short8 af[2], bf[4];
    af[0] = *(const short8*)(Ap + k0);
    af[1] = *(const short8*)(Ap + 16 * 512 + k0);
#pragma unroll
    for (int ni = 0; ni < 4; ++ni)
      bf[ni] = *(const short8*)(Bp + (size_t)ni * 16 * 512 + k0);
#pragma unroll
    for (int mi = 0; mi < 2; ++mi)
#pragma unroll
      for (int ni = 0; ni < 4; ++ni)
        acc[mi][ni] = __builtin_amdgcn_mfma_f32_16x16x32_bf16(af[mi], bf[ni], acc[mi][ni], 0, 0, 0);
  }

  float bv4[4];
#pragma unroll
  for (int ni = 0; ni < 4; ++ni) bv4[ni] = bias[nbase + ni * 16 + i16];

  if (z < 2) {
#pragma unroll
    for (int mi = 0; mi < 2; ++mi)
#pragma unroll
      for (int ni = 0; ni < 4; ++ni)
#pragma unroll
        for (int r = 0; r < 4; ++r) {
          const int m = mbase + mi * 16 + quad * 4 + r;
          const int n = nbase + ni * 16 + i16;
          ((z == 0) ? Qo : Ko)[(size_t)m * 512 + n] = f2bf(acc[mi][ni][r] + bv4[ni]);
        }
  } else {
    // direct Vt [B,H,64c,1024s] write: lane's 4 regs are 4 consecutive s
#pragma unroll
    for (int mi = 0; mi < 2; ++mi)
#pragma unroll
      for (int ni = 0; ni < 4; ++ni) {
        const int m = mbase + mi * 16 + quad * 4;
        const int b = m >> 10;
        const int s = m & 1023;
        const int n = nbase + ni * 16 + i16;
        const int h = n >> 6;
        const int c = n & 63;
        ushort4 pk;
        pk.x = f2bf(acc[mi][ni][0] + bv4[ni]);
        pk.y = f2bf(acc[mi][ni][1] + bv4[ni]);
        pk.z = f2bf(acc[mi][ni][2] + bv4[ni]);
        pk.w = f2bf(acc[mi][ni][3] + bv4[ni]);
        *(ushort4*)(VtO + (((size_t)b * NH + h) * DK + c) * S_LEN + s) = pk;
      }
  }
}

// ---------------------------------------------------------------------------
// Output GEMM: X = Obf @ Wot^T + bo + R (fp32 out). R3 tile shape.
// ---------------------------------------------------------------------------
__global__ __launch_bounds__(256) void gemm_out_kern(
    const ushort* __restrict__ A, const ushort* __restrict__ Wt,
    const float* __restrict__ bias, const float* __restrict__ R,
    float* __restrict__ X)
{
  const int t = threadIdx.x;
  const int w = t >> 6;
  const int lane = t & 63;
  const int quad = lane >> 4;
  const int i16 = lane & 15;
  const int mbase = blockIdx.x * 128 + w * 32;
  const int nbase = blockIdx.y * 64;

  floatx4 acc[2][4];
#pragma unroll
  for (int mi = 0; mi < 2; ++mi)
#pragma unroll
    for (int ni = 0; ni < 4; ++ni) acc[mi][ni] = (floatx4)(0.f);

  const ushort* Ap = A + (size_t)(mbase + i16) * 512 + quad * 8;
  const ushort* Bp = Wt + (size_t)(nbase + i16) * 512 + quad * 8;

#pragma unroll 4
  for (int k0 = 0; k0 < 512; k0 += 32) {
    short8 af[2], bf[4];
    af[0] = *(const short8*)(Ap + k0);
    af[1] = *(const short8*)(Ap + 16 * 512 + k0);
#pragma unroll
    for (int ni = 0; ni < 4; ++ni)
      bf[ni] = *(const short8*)(Bp + (size_t)ni * 16 * 512 + k0);
#pragma unroll
    for (int mi = 0; mi < 2; ++mi)
#pragma unroll
      for (int ni = 0; ni < 4; ++ni)
        acc[mi][ni] = __builtin_amdgcn_mfma_f32_16x16x32_bf16(af[mi], bf[ni], acc[mi][ni], 0, 0, 0);
  }

  float bv4[4];
#pragma unroll
  for (int ni = 0; ni < 4; ++ni) bv4[ni] = bias[nbase + ni * 16 + i16];
#pragma unroll
  for (int mi = 0; mi < 2; ++mi)
#pragma unroll
    for (int ni = 0; ni < 4; ++ni)
#pragma unroll
      for (int r = 0; r < 4; ++r) {
        const int m = mbase + mi * 16 + quad * 4 + r;
        const int n = nbase + ni * 16 + i16;
        X[(size_t)m * 512 + n] = acc[mi][ni][r] + bv4[ni] + R[(size_t)m * 512 + n];
      }
}

// ---------------------------------------------------------------------------
// MFMA dual-score causal attention; LDS-staged K/Kr/V tiles SHARED by the
// block's 4 waves (R4/R3 re-fetched per wave from L2 -> latency-bound).
// Block = 4 waves = 64 q rows of one (b,h); wave owns 16 rows. Grid (16,64).
// Block k-trip = qtile+1 (every tile at least partially needed by every wave).
// Fixed-max softmax (scores bounded), per-lane l, epilogue-only reductions.
// LDS tiles 64x64 bf16, 16B-chunk XOR swizzle (chunk ^= row&7) -> 2-way reads.
// ---------------------------------------------------------------------------
__global__ __launch_bounds__(256) void attn_kern(
    const ushort* __restrict__ Qb, const ushort* __restrict__ Kb,
    const ushort* __restrict__ VtG, const ushort* __restrict__ qraw,
    const ushort* __restrict__ kraw,
    const unsigned long long* __restrict__ mbits,
    const float* __restrict__ gammas, ushort* __restrict__ Obf)
{
  __shared__ __align__(16) ushort Kp[64][64];
  __shared__ __align__(16) ushort Kr[64][64];
  __shared__ __align__(16) ushort Vc[64][64];
  __shared__ __align__(16) ushort Pl[4][16][64];

  const int t = threadIdx.x;
  const int w = t >> 6;
  const int lane = t & 63;
  const int quad = lane >> 4;
  const int i16 = lane & 15;
  const int bh = blockIdx.y;
  const int b = bh >> 3;
  const int h = bh & 7;
  const int qt = blockIdx.x;          // 0..15
  const int qbase = qt * 64 + w * 16;

  const float gam = gammas[h];
  float te = __expf(-log1pf(__expf(gam)));
  te = fminf(fmaxf(te, 1e-5f), 1e5f);
  const float sscale = te * 0.044194173824159216f;  // te / sqrt(512)

  // Q fragments (proj + raw), held across the k-loop
  short8 Qp[2], Qr[2];
  {
    const ushort* qp = Qb + ((size_t)b * S_LEN + qbase + i16) * D_MOD + h * DK + quad * 8;
    const ushort* qq = qraw + ((size_t)b * S_LEN + qbase + i16) * D_MOD + h * DK + quad * 8;
#pragma unroll
    for (int s = 0; s < 2; ++s) {
      Qp[s] = *(const short8*)(qp + s * 32);
      Qr[s] = *(const short8*)(qq + s * 32);
    }
  }

  floatx4 Oacc[4];
#pragma unroll
  for (int t4 = 0; t4 < 4; ++t4) Oacc[t4] = (floatx4)(0.f);
  float l_run[4] = {0.f, 0.f, 0.f, 0.f};

  const int xi = i16 & 7;             // read-side chunk xor
  const int rr = t >> 3;              // staging row 0..31
  const int lc = t & 7;               // staging logical chunk
  const int pc = ((lc ^ (rr & 7)) * 8);  // physical chunk offset (shorts)

  const int nit = qt + 1;
  for (int kt = 0; kt < nit; ++kt) {
    const int k0 = kt * 64;

    // ---- global loads for staging (issued before barrier) ----
    const ushort* kpg = Kb + ((size_t)b * S_LEN + k0 + rr) * D_MOD + h * DK + lc * 8;
    const ushort* krg = kraw + ((size_t)b * S_LEN + k0 + rr) * D_MOD + h * DK + lc * 8;
    const ushort* vg  = VtG + ((size_t)bh * DK + rr) * S_LEN + k0 + lc * 8;
    short8 kpv0 = *(const short8*)kpg;
    short8 kpv1 = *(const short8*)(kpg + 32 * D_MOD);
    short8 krv0 = *(const short8*)krg;
    short8 krv1 = *(const short8*)(krg + 32 * D_MOD);
    short8 vv0  = *(const short8*)vg;
    short8 vv1  = *(const short8*)(vg + 32 * S_LEN);
    unsigned long long mw[4];
#pragma unroll
    for (int r = 0; r < 4; ++r)
      mw[r] = mbits[((size_t)b * S_LEN + qbase + quad * 4 + r) * 16 + kt];

    __syncthreads();   // previous iter's LDS readers done
    *(short8*)&Kp[rr][pc] = kpv0;
    *(short8*)&Kp[rr + 32][pc] = kpv1;
    *(short8*)&Kr[rr][pc] = krv0;
    *(short8*)&Kr[rr + 32][pc] = krv1;
    *(short8*)&Vc[rr][pc] = vv0;
    *(short8*)&Vc[rr + 32][pc] = vv1;
    __syncthreads();   // tiles visible

    // ---- scores: 16 MFMAs from LDS ----
    floatx4 accp[4], accr[4];
#pragma unroll
    for (int t4 = 0; t4 < 4; ++t4) { accp[t4] = (floatx4)(0.f); accr[t4] = (floatx4)(0.f); }
#pragma unroll
    for (int s = 0; s < 2; ++s) {
      const int co = ((s * 4 + quad) ^ xi) * 8;
      short8 kp4[4], kr4[4];
#pragma unroll
      for (int t4 = 0; t4 < 4; ++t4) kp4[t4] = *(const short8*)&Kp[t4 * 16 + i16][co];
#pragma unroll
      for (int t4 = 0; t4 < 4; ++t4) kr4[t4] = *(const short8*)&Kr[t4 * 16 + i16][co];
#pragma unroll
      for (int t4 = 0; t4 < 4; ++t4)
        accp[t4] = __builtin_amdgcn_mfma_f32_16x16x32_bf16(Qp[s], kp4[t4], accp[t4], 0, 0, 0);
#pragma unroll
      for (int t4 = 0; t4 < 4; ++t4)
        accr[t4] = __builtin_amdgcn_mfma_f32_16x16x32_bf16(Qr[s], kr4[t4], accr[t4], 0, 0, 0);
    }

    // ---- combine + exp (fixed max), P -> per-wave LDS ----
#pragma unroll
    for (int r = 0; r < 4; ++r) {
      const int qg = qbase + quad * 4 + r;
      const int prow = quad * 4 + r;
#pragma unroll
      for (int t4 = 0; t4 < 4; ++t4) {
        const int kg = k0 + t4 * 16 + i16;
        const float bitf = ((mw[r] >> (t4 * 16 + i16)) & 1ULL) ? sscale : 0.f;
        const float sv = accp[t4][r] * 0.125f + accr[t4][r] * bitf;
        const float p = (kg < qg) ? __expf(sv) : 0.f;
        l_run[r] += p;
        const int kc = t4 * 2 + (i16 >> 3);
        Pl[w][prow][((kc ^ (prow & 7)) * 8) + (i16 & 7)] = f2bf(p);
      }
    }

    // ---- PV: 8 MFMAs (A = P rows, B^T = Vc rows) ----
#pragma unroll
    for (int s = 0; s < 2; ++s) {
      const int co = ((s * 4 + quad) ^ xi) * 8;
      short8 a = *(const short8*)&Pl[w][i16][co];
#pragma unroll
      for (int t4 = 0; t4 < 4; ++t4) {
        short8 bv8 = *(const short8*)&Vc[t4 * 16 + i16][co];
        Oacc[t4] = __builtin_amdgcn_mfma_f32_16x16x32_bf16(a, bv8, Oacc[t4], 0, 0, 0);
      }
    }
  }

  // ---- epilogue: reduce l across 16 lanes, normalize, write O bf16 ----
#pragma unroll
  for (int r = 0; r < 4; ++r) {
    float l = l_run[r];
#pragma unroll
    for (int off = 1; off < 16; off <<= 1) l += __shfl_xor(l, off);
    const float inv = (l > 0.f) ? 1.f / l : 0.f;
    ushort* orow = Obf + ((size_t)b * S_LEN + qbase + quad * 4 + r) * D_MOD + h * DK;
#pragma unroll
    for (int t4 = 0; t4 < 4; ++t4)
      orow[t4 * 16 + i16] = f2bf(Oacc[t4][r] * inv);
  }
}

// ---------------------------------------------------------------------------
// LayerNorm over D=512, one wave per row.
// ---------------------------------------------------------------------------
__global__ __launch_bounds__(256) void ln_kern(
    const float* __restrict__ X, const float* __restrict__ gw,
    const float* __restrict__ bw, float* __restrict__ out)
{
  const int row = blockIdx.x * 4 + (threadIdx.x >> 6);
  const int lane = threadIdx.x & 63;
  const int c = lane * 8;
  const float* xp = &X[(size_t)row * D_MOD + c];
  const float4 x0 = *(const float4*)xp;
  const float4 x1 = *(const float4*)(xp + 4);
  float xv[8] = {x0.x, x0.y, x0.z, x0.w, x1.x, x1.y, x1.z, x1.w};
  float sum = 0.f;
#pragma unroll
  for (int u = 0; u < 8; ++u) sum += xv[u];
#pragma unroll
  for (int off = 1; off < 64; off <<= 1) sum += __shfl_xor(sum, off, 64);
  const float mu = sum * (1.f / 512.f);
  float ss = 0.f;
#pragma unroll
  for (int u = 0; u < 8; ++u) { xv[u] -= mu; ss += xv[u] * xv[u]; }
#pragma unroll
  for (int off = 1; off < 64; off <<= 1) ss += __shfl_xor(ss, off, 64);
  const float rstd = rsqrtf(ss * (1.f / 512.f) + 1e-5f);
  const float4 g0 = *(const float4*)&gw[c];
  const float4 g1 = *(const float4*)&gw[c + 4];
  const float4 b0 = *(const float4*)&bw[c];
  const float4 b1 = *(const float4*)&bw[c + 4];
  float* op = &out[(size_t)row * D_MOD + c];
  *(float4*)op = make_float4(xv[0] * rstd * g0.x + b0.x,
                             xv[1] * rstd * g0.y + b0.y,
                             xv[2] * rstd * g0.z + b0.z,
                             xv[3] * rstd * g0.w + b0.w);
  *(float4*)(op + 4) = make_float4(xv[4] * rstd * g1.x + b1.x,
                                   xv[5] * rstd * g1.y + b1.y,
                                   xv[6] * rstd * g1.z + b1.z,
                                   xv[7] * rstd * g1.w + b1.w);
}

// ---------------------------------------------------------------------------
extern "C" void kernel_launch(void* const* d_in, const int* in_sizes, int n_in,
                              void* d_out, int out_size, void* d_ws, size_t ws_size,
                              hipStream_t stream)
{
  const float* q_in  = (const float*)d_in[0];
  const float* k_in  = (const float*)d_in[1];
  const float* v_in  = (const float*)d_in[2];
  const int*   smask = (const int*)d_in[3];
  const float* Wq = (const float*)d_in[4];
  const float* bq = (const float*)d_in[5];
  const float* Wv = (const float*)d_in[6];
  const float* bv = (const float*)d_in[7];
  const float* Wo = (const float*)d_in[8];
  const float* bo = (const float*)d_in[9];
  const float* gammas = (const float*)d_in[10];
  const float* ln_g = (const float*)d_in[11];
  const float* ln_b = (const float*)d_in[12];
  float* out = (float*)d_out;

  char* ws = (char*)d_ws;
  const size_t BF = (size_t)NB * S_LEN * D_MOD * sizeof(ushort);  // 8 MiB
  ushort* qr  = (ushort*)(ws);                 // [0,8M)
  ushort* kr  = (ushort*)(ws + BF);            // [8M,16M)
  ushort* vr  = (ushort*)(ws + 2 * BF);        // [16M,24M); Obf overlays after V-GEMM
  ushort* Obf = (ushort*)(ws + 2 * BF);
  ushort* Qbf = (ushort*)(ws + 3 * BF);        // [24M,32M)
  ushort* Kbf = (ushort*)(ws + 4 * BF);        // [32M,40M)
  ushort* Vt  = (ushort*)(ws + 5 * BF);        // [40M,48M)
  unsigned long long* mbits = (unsigned long long*)(ws + 6 * BF);      // 1 MiB
  ushort* Wqt = (ushort*)(ws + 6 * BF + (1 << 20));                    // 512 KiB
  ushort* Wvt = Wqt + 512 * 512;
  ushort* Wot = Wvt + 512 * 512;
  float*  X   = (float*)ws;                    // overlays qr+kr (dead after attn)

  const dim3 tb(256);

  cvt3_kern<<<dim3(2048, 3), tb, 0, stream>>>(q_in, k_in, v_in, qr, kr, vr);
  wtrans3_kern<<<dim3(8, 8, 3), tb, 0, stream>>>(Wq, Wv, Wo, Wqt, Wvt, Wot);
  maskbits_kern<<<dim3(2048), tb, 0, stream>>>(smask, mbits);

  gemm_qkv_kern<<<dim3(64, 8, 3), tb, 0, stream>>>(qr, kr, vr, Wqt, Wvt,
                                                   bq, bv, Qbf, Kbf, Vt);

  attn_kern<<<dim3(16, 64), tb, 0, stream>>>(Qbf, Kbf, Vt, qr, kr, mbits,
                                             gammas, Obf);

  gemm_out_kern<<<dim3(64, 8), tb, 0, stream>>>(Obf, Wot, bo, q_in, X);
  ln_kern<<<2048, tb, 0, stream>>>(X, ln_g, ln_b, out);
}

// Round 6
// 248.796 us; speedup vs baseline: 1.7160x; 1.2711x over previous
//
#include <hip/hip_runtime.h>
#include <math.h>

#define S_LEN 1024
#define D_MOD 512
#define NH 8
#define DK 64
#define NB 8

typedef __attribute__((ext_vector_type(8))) short short8;   // 8 bf16 in 4 VGPRs
typedef __attribute__((ext_vector_type(4))) float floatx4;  // MFMA accumulator

union U8 { ushort u[8]; short8 v; };

__device__ __forceinline__ ushort f2bf(float x) {
  unsigned u = __float_as_uint(x);
  unsigned r = (u + 0x7fffu + ((u >> 16) & 1u)) >> 16;  // RNE
  return (ushort)r;
}

// ---------------------------------------------------------------------------
// fp32 -> bf16 convert for q,k,v in one launch (blockIdx.y selects tensor)
// ---------------------------------------------------------------------------
__global__ __launch_bounds__(256) void cvt3_kern(
    const float* __restrict__ q, const float* __restrict__ k,
    const float* __restrict__ v, ushort* __restrict__ qo,
    ushort* __restrict__ ko, ushort* __restrict__ vo)
{
  const int z = blockIdx.y;
  const float* src = (z == 0) ? q : (z == 1) ? k : v;
  ushort* dst = (z == 0) ? qo : (z == 1) ? ko : vo;
  const int i = blockIdx.x * 256 + threadIdx.x;
  const float4 a = *((const float4*)src + i * 2);
  const float4 b = *((const float4*)src + i * 2 + 1);
  U8 o;
  o.u[0] = f2bf(a.x); o.u[1] = f2bf(a.y); o.u[2] = f2bf(a.z); o.u[3] = f2bf(a.w);
  o.u[4] = f2bf(b.x); o.u[5] = f2bf(b.y); o.u[6] = f2bf(b.z); o.u[7] = f2bf(b.w);
  *(short8*)(dst + (size_t)i * 8) = o.v;
}

// ---------------------------------------------------------------------------
// Weight transpose+convert: W fp32 [512(k),512(n)] -> Wt bf16 [512(n),512(k)]
// ---------------------------------------------------------------------------
__global__ __launch_bounds__(256) void wtrans3_kern(
    const float* __restrict__ W0, const float* __restrict__ W1,
    const float* __restrict__ W2, ushort* __restrict__ T0,
    ushort* __restrict__ T1, ushort* __restrict__ T2)
{
  const int z = blockIdx.z;
  const float* W = (z == 0) ? W0 : (z == 1) ? W1 : W2;
  ushort* Wt = (z == 0) ? T0 : (z == 1) ? T1 : T2;
  __shared__ __align__(16) ushort tile[64][72];
  const int t = threadIdx.x;
  const int n0 = blockIdx.x * 64;
  const int k0 = blockIdx.y * 64;
  {
    const int r = t >> 2;
    const int c0 = (t & 3) * 16;
    const float* p = &W[(size_t)(k0 + r) * 512 + n0 + c0];
#pragma unroll
    for (int j = 0; j < 16; ++j) tile[r][c0 + j] = f2bf(p[j]);
  }
  __syncthreads();
  {
    const int c = t >> 2;
    const int kg = (t & 3) * 16;
    U8 lo, hi;
#pragma unroll
    for (int j = 0; j < 8; ++j) lo.u[j] = tile[kg + j][c];
#pragma unroll
    for (int j = 0; j < 8; ++j) hi.u[j] = tile[kg + 8 + j][c];
    ushort* q = &Wt[(size_t)(n0 + c) * 512 + k0 + kg];
    *(short8*)q = lo.v;
    *(short8*)(q + 8) = hi.v;
  }
}

// ---------------------------------------------------------------------------
// state_mask int32 [B,S,S] -> bit words u64 [B,S,S/64] (bit k = mask!=0)
// ---------------------------------------------------------------------------
__global__ __launch_bounds__(256) void maskbits_kern(
    const int* __restrict__ smask, unsigned long long* __restrict__ mb)
{
  const int row = blockIdx.x * 4 + (threadIdx.x >> 6);
  const int lane = threadIdx.x & 63;
  const int* p = smask + (size_t)row * S_LEN;
  unsigned long long mine = 0;
#pragma unroll
  for (int r = 0; r < 16; ++r) {
    int m = p[r * 64 + lane];
    unsigned long long w = __ballot(m != 0);
    if (lane == r) mine = w;
  }
  if (lane < 16) mb[(size_t)row * 16 + lane] = mine;
}

// ---------------------------------------------------------------------------
// Batched bf16 MFMA GEMM for Q/K/V projections (blockIdx.z selects).
// Block 128m x 64n, 4 waves (32m x 64n each). The 64n x 512k weight panel is
// staged ONCE in LDS (shared by all 4 waves; R5 re-fetched it per wave from
// L2 -> latency-bound). A-frags from global with 1-deep prefetch.
// z=0/1: bf16 row-major out. z=2: write Vt [B,H,64,S] directly.
// ---------------------------------------------------------------------------
__global__ __launch_bounds__(256) void gemm_qkv_kern(
    const ushort* __restrict__ qr, const ushort* __restrict__ kr,
    const ushort* __restrict__ vr, const ushort* __restrict__ Wqt,
    const ushort* __restrict__ Wvt, const float* __restrict__ bq,
    const float* __restrict__ bv, ushort* __restrict__ Qo,
    ushort* __restrict__ Ko, ushort* __restrict__ VtO)
{
  __shared__ __align__(16) ushort Bl[64][520];  // 64n x 512k, +8 pad (65 KB)

  const int z = blockIdx.z;
  const ushort* A = (z == 0) ? qr : (z == 1) ? kr : vr;
  const ushort* Wt = (z == 2) ? Wvt : Wqt;
  const float* bias = (z == 2) ? bv : bq;

  const int t = threadIdx.x;
  const int w = t >> 6;
  const int lane = t & 63;
  const int quad = lane >> 4;
  const int i16 = lane & 15;
  const int mbase = blockIdx.x * 128 + w * 32;
  const int nbase = blockIdx.y * 64;

  // ---- stage B panel ----
  {
    const int srow = t >> 2;            // 0..63
    const int scol = (t & 3) * 128;     // 0..384
    const ushort* wp = Wt + (size_t)(nbase + srow) * 512 + scol;
#pragma unroll
    for (int j = 0; j < 16; ++j)
      *(short8*)&Bl[srow][scol + j * 8] = *(const short8*)(wp + j * 8);
  }
  __syncthreads();

  floatx4 acc[2][4];
#pragma unroll
  for (int mi = 0; mi < 2; ++mi)
#pragma unroll
    for (int ni = 0; ni < 4; ++ni) acc[mi][ni] = (floatx4)(0.f);

  const ushort* Ap = A + (size_t)(mbase + i16) * 512 + quad * 8;
  short8 a0 = *(const short8*)Ap;
  short8 a1 = *(const short8*)(Ap + 16 * 512);

#pragma unroll 4
  for (int k0 = 0; k0 < 512; k0 += 32) {
    // 1-deep A prefetch (last iter overreads 32 shorts into the next
    // workspace buffer -- allocated, result unused)
    short8 na0 = *(const short8*)(Ap + k0 + 32);
    short8 na1 = *(const short8*)(Ap + 16 * 512 + k0 + 32);
    short8 bf[4];
#pragma unroll
    for (int ni = 0; ni < 4; ++ni)
      bf[ni] = *(const short8*)&Bl[ni * 16 + i16][k0 + quad * 8];
#pragma unroll
    for (int ni = 0; ni < 4; ++ni) {
      acc[0][ni] = __builtin_amdgcn_mfma_f32_16x16x32_bf16(a0, bf[ni], acc[0][ni], 0, 0, 0);
      acc[1][ni] = __builtin_amdgcn_mfma_f32_16x16x32_bf16(a1, bf[ni], acc[1][ni], 0, 0, 0);
    }
    a0 = na0;
    a1 = na1;
  }

  float bv4[4];
#pragma unroll
  for (int ni = 0; ni < 4; ++ni) bv4[ni] = bias[nbase + ni * 16 + i16];

  if (z < 2) {
    ushort* C = (z == 0) ? Qo : Ko;
#pragma unroll
    for (int mi = 0; mi < 2; ++mi)
#pragma unroll
      for (int ni = 0; ni < 4; ++ni)
#pragma unroll
        for (int r = 0; r < 4; ++r) {
          const int m = mbase + mi * 16 + quad * 4 + r;
          const int n = nbase + ni * 16 + i16;
          C[(size_t)m * 512 + n] = f2bf(acc[mi][ni][r] + bv4[ni]);
        }
  } else {
    // direct Vt [B,H,64c,1024s] write: lane's 4 regs are 4 consecutive s
#pragma unroll
    for (int mi = 0; mi < 2; ++mi)
#pragma unroll
      for (int ni = 0; ni < 4; ++ni) {
        const int m = mbase + mi * 16 + quad * 4;
        const int b = m >> 10;
        const int s = m & 1023;
        const int n = nbase + ni * 16 + i16;
        const int h = n >> 6;
        const int c = n & 63;
        ushort4 pk;
        pk.x = f2bf(acc[mi][ni][0] + bv4[ni]);
        pk.y = f2bf(acc[mi][ni][1] + bv4[ni]);
        pk.z = f2bf(acc[mi][ni][2] + bv4[ni]);
        pk.w = f2bf(acc[mi][ni][3] + bv4[ni]);
        *(ushort4*)(VtO + (((size_t)b * NH + h) * DK + c) * S_LEN + s) = pk;
      }
  }
}

// ---------------------------------------------------------------------------
// Output GEMM: X = Obf @ Wot^T + bo + R (fp32 out). Same LDS B-panel scheme.
// ---------------------------------------------------------------------------
__global__ __launch_bounds__(256) void gemm_out_kern(
    const ushort* __restrict__ A, const ushort* __restrict__ Wt,
    const float* __restrict__ bias, const float* __restrict__ R,
    float* __restrict__ X)
{
  __shared__ __align__(16) ushort Bl[64][520];

  const int t = threadIdx.x;
  const int w = t >> 6;
  const int lane = t & 63;
  const int quad = lane >> 4;
  const int i16 = lane & 15;
  const int mbase = blockIdx.x * 128 + w * 32;
  const int nbase = blockIdx.y * 64;

  {
    const int srow = t >> 2;
    const int scol = (t & 3) * 128;
    const ushort* wp = Wt + (size_t)(nbase + srow) * 512 + scol;
#pragma unroll
    for (int j = 0; j < 16; ++j)
      *(short8*)&Bl[srow][scol + j * 8] = *(const short8*)(wp + j * 8);
  }
  __syncthreads();

  floatx4 acc[2][4];
#pragma unroll
  for (int mi = 0; mi < 2; ++mi)
#pragma unroll
    for (int ni = 0; ni < 4; ++ni) acc[mi][ni] = (floatx4)(0.f);

  const ushort* Ap = A + (size_t)(mbase + i16) * 512 + quad * 8;
  short8 a0 = *(const short8*)Ap;
  short8 a1 = *(const short8*)(Ap + 16 * 512);

#pragma unroll 4
  for (int k0 = 0; k0 < 512; k0 += 32) {
    short8 na0 = *(const short8*)(Ap + k0 + 32);
    short8 na1 = *(const short8*)(Ap + 16 * 512 + k0 + 32);
    short8 bf[4];
#pragma unroll
    for (int ni = 0; ni < 4; ++ni)
      bf[ni] = *(const short8*)&Bl[ni * 16 + i16][k0 + quad * 8];
#pragma unroll
    for (int ni = 0; ni < 4; ++ni) {
      acc[0][ni] = __builtin_amdgcn_mfma_f32_16x16x32_bf16(a0, bf[ni], acc[0][ni], 0, 0, 0);
      acc[1][ni] = __builtin_amdgcn_mfma_f32_16x16x32_bf16(a1, bf[ni], acc[1][ni], 0, 0, 0);
    }
    a0 = na0;
    a1 = na1;
  }

  float bv4[4];
#pragma unroll
  for (int ni = 0; ni < 4; ++ni) bv4[ni] = bias[nbase + ni * 16 + i16];
#pragma unroll
  for (int mi = 0; mi < 2; ++mi)
#pragma unroll
    for (int ni = 0; ni < 4; ++ni)
#pragma unroll
      for (int r = 0; r < 4; ++r) {
        const int m = mbase + mi * 16 + quad * 4 + r;
        const int n = nbase + ni * 16 + i16;
        X[(size_t)m * 512 + n] = acc[mi][ni][r] + bv4[ni] + R[(size_t)m * 512 + n];
      }
}

// ---------------------------------------------------------------------------
// MFMA dual-score causal attention; LDS-staged K/Kr/V tiles shared by 4 waves.
// Load-balanced: block (bh, p) processes q-tile p then q-tile 15-p ->
// every block exactly 17 k-iters (R5's ramp 1..16 left CUs idle in the tail).
// Grid (bh=64, p=8): linear id = p*64+bh === bh (mod 8) -> all 8 blocks of a
// head land on one XCD (heuristic), keeping its 384 KB K-set in one L2.
// Fixed-max softmax via exp2 (ln2 folded into scales), per-lane l.
// ---------------------------------------------------------------------------
__global__ __launch_bounds__(256) void attn_kern(
    const ushort* __restrict__ Qb, const ushort* __restrict__ Kb,
    const ushort* __restrict__ VtG, const ushort* __restrict__ qraw,
    const ushort* __restrict__ kraw,
    const unsigned long long* __restrict__ mbits,
    const float* __restrict__ gammas, ushort* __restrict__ Obf)
{
  __shared__ __align__(16) ushort Kp[64][64];
  __shared__ __align__(16) ushort Kr[64][64];
  __shared__ __align__(16) ushort Vc[64][64];
  __shared__ __align__(16) ushort Pl[4][16][64];

  const int t = threadIdx.x;
  const int w = t >> 6;
  const int lane = t & 63;
  const int quad = lane >> 4;
  const int i16 = lane & 15;
  const int bh = blockIdx.x;          // 0..63
  const int b = bh >> 3;
  const int h = bh & 7;
  const int p = blockIdx.y;           // 0..7

  const float gam = gammas[h];
  float te = __expf(-log1pf(__expf(gam)));
  te = fminf(fmaxf(te, 1e-5f), 1e5f);
  const float c1 = 0.125f * 1.44269504f;                    // /sqrt(dk) * log2(e)
  const float c2 = te * 0.044194173824159216f * 1.44269504f; // te/sqrt(512)*log2(e)

  const int xi = i16 & 7;             // read-side chunk xor
  const int rr = t >> 3;              // staging row 0..31
  const int lc = t & 7;               // staging logical chunk
  const int pc = ((lc ^ (rr & 7)) * 8);  // physical chunk offset (shorts)

#pragma unroll
  for (int seg = 0; seg < 2; ++seg) {
    const int qt = seg ? (15 - p) : p;
    const int qbase = qt * 64 + w * 16;

    // Q fragments (proj + raw), held across the k-loop
    short8 Qp[2], Qr[2];
    {
      const ushort* qp = Qb + ((size_t)b * S_LEN + qbase + i16) * D_MOD + h * DK + quad * 8;
      const ushort* qq = qraw + ((size_t)b * S_LEN + qbase + i16) * D_MOD + h * DK + quad * 8;
#pragma unroll
      for (int s = 0; s < 2; ++s) {
        Qp[s] = *(const short8*)(qp + s * 32);
        Qr[s] = *(const short8*)(qq + s * 32);
      }
    }

    floatx4 Oacc[4];
#pragma unroll
    for (int t4 = 0; t4 < 4; ++t4) Oacc[t4] = (floatx4)(0.f);
    float l_run[4] = {0.f, 0.f, 0.f, 0.f};

    const int nit = qt + 1;
    for (int kt = 0; kt < nit; ++kt) {
      const int k0 = kt * 64;

      // ---- global loads for staging (issued before barrier) ----
      const ushort* kpg = Kb + ((size_t)b * S_LEN + k0 + rr) * D_MOD + h * DK + lc * 8;
      const ushort* krg = kraw + ((size_t)b * S_LEN + k0 + rr) * D_MOD + h * DK + lc * 8;
      const ushort* vg  = VtG + ((size_t)bh * DK + rr) * S_LEN + k0 + lc * 8;
      short8 kpv0 = *(const short8*)kpg;
      short8 kpv1 = *(const short8*)(kpg + 32 * D_MOD);
      short8 krv0 = *(const short8*)krg;
      short8 krv1 = *(const short8*)(krg + 32 * D_MOD);
      short8 vv0  = *(const short8*)vg;
      short8 vv1  = *(const short8*)(vg + 32 * S_LEN);
      unsigned long long mw[4];
#pragma unroll
      for (int r = 0; r < 4; ++r)
        mw[r] = mbits[((size_t)b * S_LEN + qbase + quad * 4 + r) * 16 + kt];

      __syncthreads();   // previous iter's LDS readers done
      *(short8*)&Kp[rr][pc] = kpv0;
      *(short8*)&Kp[rr + 32][pc] = kpv1;
      *(short8*)&Kr[rr][pc] = krv0;
      *(short8*)&Kr[rr + 32][pc] = krv1;
      *(short8*)&Vc[rr][pc] = vv0;
      *(short8*)&Vc[rr + 32][pc] = vv1;
      __syncthreads();   // tiles visible

      // ---- scores: 16 MFMAs from LDS ----
      floatx4 accp[4], accr[4];
#pragma unroll
      for (int t4 = 0; t4 < 4; ++t4) { accp[t4] = (floatx4)(0.f); accr[t4] = (floatx4)(0.f); }
#pragma unroll
      for (int s = 0; s < 2; ++s) {
        const int co = ((s * 4 + quad) ^ xi) * 8;
        short8 kp4[4], kr4[4];
#pragma unroll
        for (int t4 = 0; t4 < 4; ++t4) kp4[t4] = *(const short8*)&Kp[t4 * 16 + i16][co];
#pragma unroll
        for (int t4 = 0; t4 < 4; ++t4) kr4[t4] = *(const short8*)&Kr[t4 * 16 + i16][co];
#pragma unroll
        for (int t4 = 0; t4 < 4; ++t4)
          accp[t4] = __builtin_amdgcn_mfma_f32_16x16x32_bf16(Qp[s], kp4[t4], accp[t4], 0, 0, 0);
#pragma unroll
        for (int t4 = 0; t4 < 4; ++t4)
          accr[t4] = __builtin_amdgcn_mfma_f32_16x16x32_bf16(Qr[s], kr4[t4], accr[t4], 0, 0, 0);
      }

      // ---- combine + exp2 (fixed max), P -> per-wave LDS ----
#pragma unroll
      for (int r = 0; r < 4; ++r) {
        const int qg = qbase + quad * 4 + r;
        const int prow = quad * 4 + r;
#pragma unroll
        for (int t4 = 0; t4 < 4; ++t4) {
          const int kg = k0 + t4 * 16 + i16;
          const float bitf = ((mw[r] >> (t4 * 16 + i16)) & 1ULL) ? c2 : 0.f;
          const float sv = accp[t4][r] * c1 + accr[t4][r] * bitf;
          const float pv = (kg < qg) ? exp2f(sv) : 0.f;
          l_run[r] += pv;
          const int kc = t4 * 2 + (i16 >> 3);
          Pl[w][prow][((kc ^ (prow & 7)) * 8) + (i16 & 7)] = f2bf(pv);
        }
      }

      // ---- PV: 8 MFMAs (A = P rows, B^T = Vc rows) ----
#pragma unroll
      for (int s = 0; s < 2; ++s) {
        const int co = ((s * 4 + quad) ^ xi) * 8;
        short8 a = *(const short8*)&Pl[w][i16][co];
#pragma unroll
        for (int t4 = 0; t4 < 4; ++t4) {
          short8 bv8 = *(const short8*)&Vc[t4 * 16 + i16][co];
          Oacc[t4] = __builtin_amdgcn_mfma_f32_16x16x32_bf16(a, bv8, Oacc[t4], 0, 0, 0);
        }
      }
    }

    // ---- epilogue: reduce l across 16 lanes, normalize, write O bf16 ----
#pragma unroll
    for (int r = 0; r < 4; ++r) {
      float l = l_run[r];
#pragma unroll
      for (int off = 1; off < 16; off <<= 1) l += __shfl_xor(l, off);
      const float inv = (l > 0.f) ? 1.f / l : 0.f;
      ushort* orow = Obf + ((size_t)b * S_LEN + qbase + quad * 4 + r) * D_MOD + h * DK;
#pragma unroll
      for (int t4 = 0; t4 < 4; ++t4)
        orow[t4 * 16 + i16] = f2bf(Oacc[t4][r] * inv);
    }
  }
}

// ---------------------------------------------------------------------------
// LayerNorm over D=512, one wave per row.
// ---------------------------------------------------------------------------
__global__ __launch_bounds__(256) void ln_kern(
    const float* __restrict__ X, const float* __restrict__ gw,
    const float* __restrict__ bw, float* __restrict__ out)
{
  const int row = blockIdx.x * 4 + (threadIdx.x >> 6);
  const int lane = threadIdx.x & 63;
  const int c = lane * 8;
  const float* xp = &X[(size_t)row * D_MOD + c];
  const float4 x0 = *(const float4*)xp;
  const float4 x1 = *(const float4*)(xp + 4);
  float xv[8] = {x0.x, x0.y, x0.z, x0.w, x1.x, x1.y, x1.z, x1.w};
  float sum = 0.f;
#pragma unroll
  for (int u = 0; u < 8; ++u) sum += xv[u];
#pragma unroll
  for (int off = 1; off < 64; off <<= 1) sum += __shfl_xor(sum, off, 64);
  const float mu = sum * (1.f / 512.f);
  float ss = 0.f;
#pragma unroll
  for (int u = 0; u < 8; ++u) { xv[u] -= mu; ss += xv[u] * xv[u]; }
#pragma unroll
  for (int off = 1; off < 64; off <<= 1) ss += __shfl_xor(ss, off, 64);
  const float rstd = rsqrtf(ss * (1.f / 512.f) + 1e-5f);
  const float4 g0 = *(const float4*)&gw[c];
  const float4 g1 = *(const float4*)&gw[c + 4];
  const float4 b0 = *(const float4*)&bw[c];
  const float4 b1 = *(const float4*)&bw[c + 4];
  float* op = &out[(size_t)row * D_MOD + c];
  *(float4*)op = make_float4(xv[0] * rstd * g0.x + b0.x,
                             xv[1] * rstd * g0.y + b0.y,
                             xv[2] * rstd * g0.z + b0.z,
                             xv[3] * rstd * g0.w + b0.w);
  *(float4*)(op + 4) = make_float4(xv[4] * rstd * g1.x + b1.x,
                                   xv[5] * rstd * g1.y + b1.y,
                                   xv[6] * rstd * g1.z + b1.z,
                                   xv[7] * rstd * g1.w + b1.w);
}

// ---------------------------------------------------------------------------
extern "C" void kernel_launch(void* const* d_in, const int* in_sizes, int n_in,
                              void* d_out, int out_size, void* d_ws, size_t ws_size,
                              hipStream_t stream)
{
  const float* q_in  = (const float*)d_in[0];
  const float* k_in  = (const float*)d_in[1];
  const float* v_in  = (const float*)d_in[2];
  const int*   smask = (const int*)d_in[3];
  const float* Wq = (const float*)d_in[4];
  const float* bq = (const float*)d_in[5];
  const float* Wv = (const float*)d_in[6];
  const float* bv = (const float*)d_in[7];
  const float* Wo = (const float*)d_in[8];
  const float* bo = (const float*)d_in[9];
  const float* gammas = (const float*)d_in[10];
  const float* ln_g = (const float*)d_in[11];
  const float* ln_b = (const float*)d_in[12];
  float* out = (float*)d_out;

  char* ws = (char*)d_ws;
  const size_t BF = (size_t)NB * S_LEN * D_MOD * sizeof(ushort);  // 8 MiB
  ushort* qr  = (ushort*)(ws);                 // [0,8M)
  ushort* kr  = (ushort*)(ws + BF);            // [8M,16M)
  ushort* vr  = (ushort*)(ws + 2 * BF);        // [16M,24M); Obf overlays after V-GEMM
  ushort* Obf = (ushort*)(ws + 2 * BF);
  ushort* Qbf = (ushort*)(ws + 3 * BF);        // [24M,32M)
  ushort* Kbf = (ushort*)(ws + 4 * BF);        // [32M,40M)
  ushort* Vt  = (ushort*)(ws + 5 * BF);        // [40M,48M)
  unsigned long long* mbits = (unsigned long long*)(ws + 6 * BF);      // 1 MiB
  ushort* Wqt = (ushort*)(ws + 6 * BF + (1 << 20));                    // 512 KiB
  ushort* Wvt = Wqt + 512 * 512;
  ushort* Wot = Wvt + 512 * 512;
  float*  X   = (float*)ws;                    // overlays qr+kr (dead after attn)

  const dim3 tb(256);

  cvt3_kern<<<dim3(2048, 3), tb, 0, stream>>>(q_in, k_in, v_in, qr, kr, vr);
  wtrans3_kern<<<dim3(8, 8, 3), tb, 0, stream>>>(Wq, Wv, Wo, Wqt, Wvt, Wot);
  maskbits_kern<<<dim3(2048), tb, 0, stream>>>(smask, mbits);

  gemm_qkv_kern<<<dim3(64, 8, 3), tb, 0, stream>>>(qr, kr, vr, Wqt, Wvt,
                                                   bq, bv, Qbf, Kbf, Vt);

  attn_kern<<<dim3(64, 8), tb, 0, stream>>>(Qbf, Kbf, Vt, qr, kr, mbits,
                                            gammas, Obf);

  gemm_out_kern<<<dim3(64, 8), tb, 0, stream>>>(Obf, Wot, bo, q_in, X);
  ln_kern<<<2048, tb, 0, stream>>>(X, ln_g, ln_b, out);
}

// Round 7
// 231.234 us; speedup vs baseline: 1.8463x; 1.0759x over previous
//
#include <hip/hip_runtime.h>
#include <math.h>

#define S_LEN 1024
#define D_MOD 512
#define NH 8
#define DK 64
#define NB 8

typedef __attribute__((ext_vector_type(8))) short short8;   // 8 bf16 in 4 VGPRs
typedef __attribute__((ext_vector_type(4))) float floatx4;  // MFMA accumulator

union U8 { ushort u[8]; short8 v; };

__device__ __forceinline__ ushort f2bf(float x) {
  unsigned u = __float_as_uint(x);
  unsigned r = (u + 0x7fffu + ((u >> 16) & 1u)) >> 16;  // RNE
  return (ushort)r;
}

// ---------------------------------------------------------------------------
// Fused prep: y=0..2 -> fp32->bf16 convert of q/k/v; y=3 -> mask bit-pack.
// ---------------------------------------------------------------------------
__global__ __launch_bounds__(256) void prep_kern(
    const float* __restrict__ q, const float* __restrict__ k,
    const float* __restrict__ v, const int* __restrict__ smask,
    ushort* __restrict__ qo, ushort* __restrict__ ko,
    ushort* __restrict__ vo, unsigned long long* __restrict__ mb)
{
  const int y = blockIdx.y;
  const int t = threadIdx.x;
  if (y < 3) {
    const float* src = (y == 0) ? q : (y == 1) ? k : v;
    ushort* dst = (y == 0) ? qo : (y == 1) ? ko : vo;
    const int i = blockIdx.x * 256 + t;
    const float4 a = *((const float4*)src + i * 2);
    const float4 b = *((const float4*)src + i * 2 + 1);
    U8 o;
    o.u[0] = f2bf(a.x); o.u[1] = f2bf(a.y); o.u[2] = f2bf(a.z); o.u[3] = f2bf(a.w);
    o.u[4] = f2bf(b.x); o.u[5] = f2bf(b.y); o.u[6] = f2bf(b.z); o.u[7] = f2bf(b.w);
    *(short8*)(dst + (size_t)i * 8) = o.v;
  } else {
    const int row = blockIdx.x * 4 + (t >> 6);
    const int lane = t & 63;
    const int* p = smask + (size_t)row * S_LEN;
    unsigned long long mine = 0;
#pragma unroll
    for (int r = 0; r < 16; ++r) {
      int m = p[r * 64 + lane];
      unsigned long long w = __ballot(m != 0);
      if (lane == r) mine = w;
    }
    if (lane < 16) mb[(size_t)row * 16 + lane] = mine;
  }
}

// ---------------------------------------------------------------------------
// Weight transpose+convert: W fp32 [512(k),512(n)] -> Wt bf16 [512(n),512(k)]
// ---------------------------------------------------------------------------
__global__ __launch_bounds__(256) void wtrans3_kern(
    const float* __restrict__ W0, const float* __restrict__ W1,
    const float* __restrict__ W2, ushort* __restrict__ T0,
    ushort* __restrict__ T1, ushort* __restrict__ T2)
{
  const int z = blockIdx.z;
  const float* W = (z == 0) ? W0 : (z == 1) ? W1 : W2;
  ushort* Wt = (z == 0) ? T0 : (z == 1) ? T1 : T2;
  __shared__ __align__(16) ushort tile[64][72];
  const int t = threadIdx.x;
  const int n0 = blockIdx.x * 64;
  const int k0 = blockIdx.y * 64;
  {
    const int r = t >> 2;
    const int c0 = (t & 3) * 16;
    const float* p = &W[(size_t)(k0 + r) * 512 + n0 + c0];
#pragma unroll
    for (int j = 0; j < 16; ++j) tile[r][c0 + j] = f2bf(p[j]);
  }
  __syncthreads();
  {
    const int c = t >> 2;
    const int kg = (t & 3) * 16;
    U8 lo, hi;
#pragma unroll
    for (int j = 0; j < 8; ++j) lo.u[j] = tile[kg + j][c];
#pragma unroll
    for (int j = 0; j < 8; ++j) hi.u[j] = tile[kg + 8 + j][c];
    ushort* q = &Wt[(size_t)(n0 + c) * 512 + k0 + kg];
    *(short8*)q = lo.v;
    *(short8*)(q + 8) = hi.v;
  }
}

// ---------------------------------------------------------------------------
// bf16 MFMA GEMM, double-buffered B-tile (64n x 64k, XOR-swizzled, 16 KB LDS),
// A wave-private in regs with 2-iter-deep prefetch. Block 128m x 64n, 4 waves
// (32m x 64n each). BK=64, 8 iters, 1 barrier/iter.
// z=0/1: bf16 row-major out. z=2: write Vt [B,H,64,S] directly.
// ---------------------------------------------------------------------------
__global__ __launch_bounds__(256) void gemm_qkv_kern(
    const ushort* __restrict__ qr, const ushort* __restrict__ kr,
    const ushort* __restrict__ vr, const ushort* __restrict__ Wqt,
    const ushort* __restrict__ Wvt, const float* __restrict__ bq,
    const float* __restrict__ bv, ushort* __restrict__ Qo,
    ushort* __restrict__ Ko, ushort* __restrict__ VtO)
{
  __shared__ __align__(16) ushort Bl[2][64][64];

  const int z = blockIdx.z;
  const ushort* A = (z == 0) ? qr : (z == 1) ? kr : vr;
  const ushort* Wt = (z == 2) ? Wvt : Wqt;
  const float* bias = (z == 2) ? bv : bq;

  const int t = threadIdx.x;
  const int w = t >> 6;
  const int lane = t & 63;
  const int quad = lane >> 4;
  const int i16 = lane & 15;
  const int mbase = blockIdx.x * 128 + w * 32;
  const int nbase = blockIdx.y * 64;

  // staging geometry: thread -> B row r, logical chunks lc, lc+1
  const int sr = t >> 2;
  const int slc = (t & 3) * 2;
  const int sp0 = ((slc ^ (sr & 7)) * 8);
  const int sp1 = (((slc + 1) ^ (sr & 7)) * 8);
  const ushort* Bg = Wt + (size_t)(nbase + sr) * 512 + (t & 3) * 16;
  const int xb = i16 & 7;

  const ushort* Ap = A + (size_t)(mbase + i16) * 512 + quad * 8;

  floatx4 acc[2][4];
#pragma unroll
  for (int mi = 0; mi < 2; ++mi)
#pragma unroll
    for (int ni = 0; ni < 4; ++ni) acc[mi][ni] = (floatx4)(0.f);

  short8 areg[3][2][2];  // depth, mi, kc
#pragma unroll
  for (int d = 0; d < 2; ++d)
#pragma unroll
    for (int mi = 0; mi < 2; ++mi)
#pragma unroll
      for (int kc = 0; kc < 2; ++kc)
        areg[d][mi][kc] = *(const short8*)(Ap + d * 64 + kc * 32 + mi * 16 * 512);

  // prologue: stage B tile 0
  {
    short8 b0 = *(const short8*)Bg;
    short8 b1 = *(const short8*)(Bg + 8);
    *(short8*)&Bl[0][sr][sp0] = b0;
    *(short8*)&Bl[0][sr][sp1] = b1;
    __syncthreads();
  }

#pragma unroll
  for (int kt = 0; kt < 8; ++kt) {
    const int cb = kt & 1;
    short8 nb0, nb1;
    if (kt < 7) {
      nb0 = *(const short8*)(Bg + (kt + 1) * 64);
      nb1 = *(const short8*)(Bg + (kt + 1) * 64 + 8);
    }
    if (kt < 6) {
#pragma unroll
      for (int mi = 0; mi < 2; ++mi)
#pragma unroll
        for (int kc = 0; kc < 2; ++kc)
          areg[(kt + 2) % 3][mi][kc] =
              *(const short8*)(Ap + (kt + 2) * 64 + kc * 32 + mi * 16 * 512);
    }
    short8 bf[2][4];
#pragma unroll
    for (int kc = 0; kc < 2; ++kc)
#pragma unroll
      for (int ni = 0; ni < 4; ++ni)
        bf[kc][ni] = *(const short8*)&Bl[cb][ni * 16 + i16][((kc * 4 + quad) ^ xb) * 8];
#pragma unroll
    for (int kc = 0; kc < 2; ++kc)
#pragma unroll
      for (int mi = 0; mi < 2; ++mi)
#pragma unroll
        for (int ni = 0; ni < 4; ++ni)
          acc[mi][ni] = __builtin_amdgcn_mfma_f32_16x16x32_bf16(
              areg[kt % 3][mi][kc], bf[kc][ni], acc[mi][ni], 0, 0, 0);
    if (kt < 7) {
      *(short8*)&Bl[cb ^ 1][sr][sp0] = nb0;
      *(short8*)&Bl[cb ^ 1][sr][sp1] = nb1;
      __syncthreads();
    }
  }

  float bv4[4];
#pragma unroll
  for (int ni = 0; ni < 4; ++ni) bv4[ni] = bias[nbase + ni * 16 + i16];

  if (z < 2) {
    ushort* C = (z == 0) ? Qo : Ko;
#pragma unroll
    for (int mi = 0; mi < 2; ++mi)
#pragma unroll
      for (int ni = 0; ni < 4; ++ni)
#pragma unroll
        for (int r = 0; r < 4; ++r) {
          const int m = mbase + mi * 16 + quad * 4 + r;
          const int n = nbase + ni * 16 + i16;
          C[(size_t)m * 512 + n] = f2bf(acc[mi][ni][r] + bv4[ni]);
        }
  } else {
#pragma unroll
    for (int mi = 0; mi < 2; ++mi)
#pragma unroll
      for (int ni = 0; ni < 4; ++ni) {
        const int m = mbase + mi * 16 + quad * 4;
        const int b = m >> 10;
        const int s = m & 1023;
        const int n = nbase + ni * 16 + i16;
        const int h = n >> 6;
        const int c = n & 63;
        ushort4 pk;
        pk.x = f2bf(acc[mi][ni][0] + bv4[ni]);
        pk.y = f2bf(acc[mi][ni][1] + bv4[ni]);
        pk.z = f2bf(acc[mi][ni][2] + bv4[ni]);
        pk.w = f2bf(acc[mi][ni][3] + bv4[ni]);
        *(ushort4*)(VtO + (((size_t)b * NH + h) * DK + c) * S_LEN + s) = pk;
      }
  }
}

// ---------------------------------------------------------------------------
// Output GEMM: X = Obf @ Wot^T + bo + R (fp32 out). Same dbuf structure.
// ---------------------------------------------------------------------------
__global__ __launch_bounds__(256) void gemm_out_kern(
    const ushort* __restrict__ A, const ushort* __restrict__ Wt,
    const float* __restrict__ bias, const float* __restrict__ R,
    float* __restrict__ X)
{
  __shared__ __align__(16) ushort Bl[2][64][64];

  const int t = threadIdx.x;
  const int w = t >> 6;
  const int lane = t & 63;
  const int quad = lane >> 4;
  const int i16 = lane & 15;
  const int mbase = blockIdx.x * 128 + w * 32;
  const int nbase = blockIdx.y * 64;

  const int sr = t >> 2;
  const int slc = (t & 3) * 2;
  const int sp0 = ((slc ^ (sr & 7)) * 8);
  const int sp1 = (((slc + 1) ^ (sr & 7)) * 8);
  const ushort* Bg = Wt + (size_t)(nbase + sr) * 512 + (t & 3) * 16;
  const int xb = i16 & 7;

  const ushort* Ap = A + (size_t)(mbase + i16) * 512 + quad * 8;

  floatx4 acc[2][4];
#pragma unroll
  for (int mi = 0; mi < 2; ++mi)
#pragma unroll
    for (int ni = 0; ni < 4; ++ni) acc[mi][ni] = (floatx4)(0.f);

  short8 areg[3][2][2];
#pragma unroll
  for (int d = 0; d < 2; ++d)
#pragma unroll
    for (int mi = 0; mi < 2; ++mi)
#pragma unroll
      for (int kc = 0; kc < 2; ++kc)
        areg[d][mi][kc] = *(const short8*)(Ap + d * 64 + kc * 32 + mi * 16 * 512);

  {
    short8 b0 = *(const short8*)Bg;
    short8 b1 = *(const short8*)(Bg + 8);
    *(short8*)&Bl[0][sr][sp0] = b0;
    *(short8*)&Bl[0][sr][sp1] = b1;
    __syncthreads();
  }

#pragma unroll
  for (int kt = 0; kt < 8; ++kt) {
    const int cb = kt & 1;
    short8 nb0, nb1;
    if (kt < 7) {
      nb0 = *(const short8*)(Bg + (kt + 1) * 64);
      nb1 = *(const short8*)(Bg + (kt + 1) * 64 + 8);
    }
    if (kt < 6) {
#pragma unroll
      for (int mi = 0; mi < 2; ++mi)
#pragma unroll
        for (int kc = 0; kc < 2; ++kc)
          areg[(kt + 2) % 3][mi][kc] =
              *(const short8*)(Ap + (kt + 2) * 64 + kc * 32 + mi * 16 * 512);
    }
    short8 bf[2][4];
#pragma unroll
    for (int kc = 0; kc < 2; ++kc)
#pragma unroll
      for (int ni = 0; ni < 4; ++ni)
        bf[kc][ni] = *(const short8*)&Bl[cb][ni * 16 + i16][((kc * 4 + quad) ^ xb) * 8];
#pragma unroll
    for (int kc = 0; kc < 2; ++kc)
#pragma unroll
      for (int mi = 0; mi < 2; ++mi)
#pragma unroll
        for (int ni = 0; ni < 4; ++ni)
          acc[mi][ni] = __builtin_amdgcn_mfma_f32_16x16x32_bf16(
              areg[kt % 3][mi][kc], bf[kc][ni], acc[mi][ni], 0, 0, 0);
    if (kt < 7) {
      *(short8*)&Bl[cb ^ 1][sr][sp0] = nb0;
      *(short8*)&Bl[cb ^ 1][sr][sp1] = nb1;
      __syncthreads();
    }
  }

  float bv4[4];
#pragma unroll
  for (int ni = 0; ni < 4; ++ni) bv4[ni] = bias[nbase + ni * 16 + i16];
#pragma unroll
  for (int mi = 0; mi < 2; ++mi)
#pragma unroll
    for (int ni = 0; ni < 4; ++ni)
#pragma unroll
      for (int r = 0; r < 4; ++r) {
        const int m = mbase + mi * 16 + quad * 4 + r;
        const int n = nbase + ni * 16 + i16;
        X[(size_t)m * 512 + n] = acc[mi][ni][r] + bv4[ni] + R[(size_t)m * 512 + n];
      }
}

// ---------------------------------------------------------------------------
// MFMA dual-score causal attention; DOUBLE-BUFFERED LDS staging of K/Kr/V
// (next tile's global loads land during current tile's compute -> the
// vmcnt(0)+barrier drain is free). 1 barrier/iter. Diagonal-only causal
// masking. P packed by truncation (1 VALU). exp2 with folded ln2 scales.
// Block (bh, p): q-tiles p and 15-p -> 17 iters/block, XCD-pinned by bh%8.
// ---------------------------------------------------------------------------
__global__ __launch_bounds__(256) void attn_kern(
    const ushort* __restrict__ Qb, const ushort* __restrict__ Kb,
    const ushort* __restrict__ VtG, const ushort* __restrict__ qraw,
    const ushort* __restrict__ kraw,
    const unsigned long long* __restrict__ mbits,
    const float* __restrict__ gammas, ushort* __restrict__ Obf)
{
  __shared__ __align__(16) ushort Kp[2][64][64];
  __shared__ __align__(16) ushort Kr[2][64][64];
  __shared__ __align__(16) ushort Vc[2][64][64];
  __shared__ __align__(16) ushort Pl[4][16][64];

  const int t = threadIdx.x;
  const int w = t >> 6;
  const int lane = t & 63;
  const int quad = lane >> 4;
  const int i16 = lane & 15;
  const int bh = blockIdx.x;          // 0..63
  const int b = bh >> 3;
  const int h = bh & 7;
  const int p = blockIdx.y;           // 0..7

  const float gam = gammas[h];
  float te = __expf(-log1pf(__expf(gam)));
  te = fminf(fmaxf(te, 1e-5f), 1e5f);
  const float c1 = 0.125f * 1.44269504f;
  const float c2 = te * 0.044194173824159216f * 1.44269504f;

  const int xi = i16 & 7;
  const int rr = t >> 3;              // staging row 0..31
  const int lc = t & 7;
  const int pc = ((lc ^ (rr & 7)) * 8);

  const ushort* kpgB = Kb + ((size_t)b * S_LEN + rr) * D_MOD + h * DK + lc * 8;
  const ushort* krgB = kraw + ((size_t)b * S_LEN + rr) * D_MOD + h * DK + lc * 8;
  const ushort* vgB  = VtG + ((size_t)bh * DK + rr) * S_LEN + lc * 8;

#pragma unroll
  for (int seg = 0; seg < 2; ++seg) {
    const int qt = seg ? (15 - p) : p;
    const int qbase = qt * 64 + w * 16;

    short8 Qp[2], Qr[2];
    {
      const ushort* qp = Qb + ((size_t)b * S_LEN + qbase + i16) * D_MOD + h * DK + quad * 8;
      const ushort* qq = qraw + ((size_t)b * S_LEN + qbase + i16) * D_MOD + h * DK + quad * 8;
#pragma unroll
      for (int s = 0; s < 2; ++s) {
        Qp[s] = *(const short8*)(qp + s * 32);
        Qr[s] = *(const short8*)(qq + s * 32);
      }
    }

    floatx4 Oacc[4];
#pragma unroll
    for (int t4 = 0; t4 < 4; ++t4) Oacc[t4] = (floatx4)(0.f);
    float l_run[4] = {0.f, 0.f, 0.f, 0.f};

    const int nit = qt + 1;

    // ---- prologue: stage tile 0 into buffer 0 ----
    {
      short8 k0v0 = *(const short8*)kpgB;
      short8 k0v1 = *(const short8*)(kpgB + 32 * D_MOD);
      short8 r0v0 = *(const short8*)krgB;
      short8 r0v1 = *(const short8*)(krgB + 32 * D_MOD);
      short8 v0v0 = *(const short8*)vgB;
      short8 v0v1 = *(const short8*)(vgB + 32 * S_LEN);
      __syncthreads();   // prior seg's readers done
      *(short8*)&Kp[0][rr][pc] = k0v0;
      *(short8*)&Kp[0][rr + 32][pc] = k0v1;
      *(short8*)&Kr[0][rr][pc] = r0v0;
      *(short8*)&Kr[0][rr + 32][pc] = r0v1;
      *(short8*)&Vc[0][rr][pc] = v0v0;
      *(short8*)&Vc[0][rr + 32][pc] = v0v1;
      __syncthreads();
    }

    for (int kt = 0; kt < nit; ++kt) {
      const int cb = kt & 1;
      const bool havenext = (kt + 1 < nit);
      const bool diag = (kt == qt);

      // ---- prefetch next tile (global -> regs), lands during compute ----
      short8 nk0, nk1, nr0, nr1, nv0, nv1;
      if (havenext) {
        const size_t ko = (size_t)(kt + 1) * 64;
        nk0 = *(const short8*)(kpgB + ko * D_MOD);
        nk1 = *(const short8*)(kpgB + ko * D_MOD + 32 * D_MOD);
        nr0 = *(const short8*)(krgB + ko * D_MOD);
        nr1 = *(const short8*)(krgB + ko * D_MOD + 32 * D_MOD);
        nv0 = *(const short8*)(vgB + ko);
        nv1 = *(const short8*)(vgB + ko + 32 * S_LEN);
      }

      unsigned long long mw[4];
#pragma unroll
      for (int r = 0; r < 4; ++r)
        mw[r] = mbits[((size_t)b * S_LEN + qbase + quad * 4 + r) * 16 + kt];

      // ---- scores: 16 MFMAs from LDS ----
      floatx4 accp[4], accr[4];
#pragma unroll
      for (int t4 = 0; t4 < 4; ++t4) { accp[t4] = (floatx4)(0.f); accr[t4] = (floatx4)(0.f); }
#pragma unroll
      for (int s = 0; s < 2; ++s) {
        const int co = ((s * 4 + quad) ^ xi) * 8;
        short8 kp4[4], kr4[4];
#pragma unroll
        for (int t4 = 0; t4 < 4; ++t4) kp4[t4] = *(const short8*)&Kp[cb][t4 * 16 + i16][co];
#pragma unroll
        for (int t4 = 0; t4 < 4; ++t4) kr4[t4] = *(const short8*)&Kr[cb][t4 * 16 + i16][co];
#pragma unroll
        for (int t4 = 0; t4 < 4; ++t4)
          accp[t4] = __builtin_amdgcn_mfma_f32_16x16x32_bf16(Qp[s], kp4[t4], accp[t4], 0, 0, 0);
#pragma unroll
        for (int t4 = 0; t4 < 4; ++t4)
          accr[t4] = __builtin_amdgcn_mfma_f32_16x16x32_bf16(Qr[s], kr4[t4], accr[t4], 0, 0, 0);
      }

      // ---- combine + exp2, P -> per-wave LDS (truncation pack) ----
      const int k0g = kt * 64;
#pragma unroll
      for (int r = 0; r < 4; ++r) {
        const int qg = qbase + quad * 4 + r;
        const int prow = quad * 4 + r;
#pragma unroll
        for (int t4 = 0; t4 < 4; ++t4) {
          const float bitf = ((mw[r] >> (t4 * 16 + i16)) & 1ULL) ? c2 : 0.f;
          const float sv = accp[t4][r] * c1 + accr[t4][r] * bitf;
          float pv = __builtin_amdgcn_exp2f(sv);
          if (diag) {
            const int kg = k0g + t4 * 16 + i16;
            pv = (kg < qg) ? pv : 0.f;
          }
          l_run[r] += pv;
          const int kc = t4 * 2 + (i16 >> 3);
          Pl[w][prow][((kc ^ (prow & 7)) * 8) + (i16 & 7)] =
              (ushort)(__float_as_uint(pv) >> 16);
        }
      }

      // ---- PV: 8 MFMAs ----
#pragma unroll
      for (int s = 0; s < 2; ++s) {
        const int co = ((s * 4 + quad) ^ xi) * 8;
        short8 a = *(const short8*)&Pl[w][i16][co];
#pragma unroll
        for (int t4 = 0; t4 < 4; ++t4) {
          short8 bv8 = *(const short8*)&Vc[cb][t4 * 16 + i16][co];
          Oacc[t4] = __builtin_amdgcn_mfma_f32_16x16x32_bf16(a, bv8, Oacc[t4], 0, 0, 0);
        }
      }

      // ---- write next tile into the other buffer ----
      if (havenext) {
        *(short8*)&Kp[cb ^ 1][rr][pc] = nk0;
        *(short8*)&Kp[cb ^ 1][rr + 32][pc] = nk1;
        *(short8*)&Kr[cb ^ 1][rr][pc] = nr0;
        *(short8*)&Kr[cb ^ 1][rr + 32][pc] = nr1;
        *(short8*)&Vc[cb ^ 1][rr][pc] = nv0;
        *(short8*)&Vc[cb ^ 1][rr + 32][pc] = nv1;
        __syncthreads();
      }
    }

    // ---- epilogue ----
#pragma unroll
    for (int r = 0; r < 4; ++r) {
      float l = l_run[r];
#pragma unroll
      for (int off = 1; off < 16; off <<= 1) l += __shfl_xor(l, off);
      const float inv = (l > 0.f) ? 1.f / l : 0.f;
      ushort* orow = Obf + ((size_t)b * S_LEN + qbase + quad * 4 + r) * D_MOD + h * DK;
#pragma unroll
      for (int t4 = 0; t4 < 4; ++t4)
        orow[t4 * 16 + i16] = f2bf(Oacc[t4][r] * inv);
    }
  }
}

// ---------------------------------------------------------------------------
// LayerNorm over D=512, one wave per row.
// ---------------------------------------------------------------------------
__global__ __launch_bounds__(256) void ln_kern(
    const float* __restrict__ X, const float* __restrict__ gw,
    const float* __restrict__ bw, float* __restrict__ out)
{
  const int row = blockIdx.x * 4 + (threadIdx.x >> 6);
  const int lane = threadIdx.x & 63;
  const int c = lane * 8;
  const float* xp = &X[(size_t)row * D_MOD + c];
  const float4 x0 = *(const float4*)xp;
  const float4 x1 = *(const float4*)(xp + 4);
  float xv[8] = {x0.x, x0.y, x0.z, x0.w, x1.x, x1.y, x1.z, x1.w};
  float sum = 0.f;
#pragma unroll
  for (int u = 0; u < 8; ++u) sum += xv[u];
#pragma unroll
  for (int off = 1; off < 64; off <<= 1) sum += __shfl_xor(sum, off, 64);
  const float mu = sum * (1.f / 512.f);
  float ss = 0.f;
#pragma unroll
  for (int u = 0; u < 8; ++u) { xv[u] -= mu; ss += xv[u] * xv[u]; }
#pragma unroll
  for (int off = 1; off < 64; off <<= 1) ss += __shfl_xor(ss, off, 64);
  const float rstd = rsqrtf(ss * (1.f / 512.f) + 1e-5f);
  const float4 g0 = *(const float4*)&gw[c];
  const float4 g1 = *(const float4*)&gw[c + 4];
  const float4 b0 = *(const float4*)&bw[c];
  const float4 b1 = *(const float4*)&bw[c + 4];
  float* op = &out[(size_t)row * D_MOD + c];
  *(float4*)op = make_float4(xv[0] * rstd * g0.x + b0.x,
                             xv[1] * rstd * g0.y + b0.y,
                             xv[2] * rstd * g0.z + b0.z,
                             xv[3] * rstd * g0.w + b0.w);
  *(float4*)(op + 4) = make_float4(xv[4] * rstd * g1.x + b1.x,
                                   xv[5] * rstd * g1.y + b1.y,
                                   xv[6] * rstd * g1.z + b1.z,
                                   xv[7] * rstd * g1.w + b1.w);
}

// ---------------------------------------------------------------------------
extern "C" void kernel_launch(void* const* d_in, const int* in_sizes, int n_in,
                              void* d_out, int out_size, void* d_ws, size_t ws_size,
                              hipStream_t stream)
{
  const float* q_in  = (const float*)d_in[0];
  const float* k_in  = (const float*)d_in[1];
  const float* v_in  = (const float*)d_in[2];
  const int*   smask = (const int*)d_in[3];
  const float* Wq = (const float*)d_in[4];
  const float* bq = (const float*)d_in[5];
  const float* Wv = (const float*)d_in[6];
  const float* bv = (const float*)d_in[7];
  const float* Wo = (const float*)d_in[8];
  const float* bo = (const float*)d_in[9];
  const float* gammas = (const float*)d_in[10];
  const float* ln_g = (const float*)d_in[11];
  const float* ln_b = (const float*)d_in[12];
  float* out = (float*)d_out;

  char* ws = (char*)d_ws;
  const size_t BF = (size_t)NB * S_LEN * D_MOD * sizeof(ushort);  // 8 MiB
  ushort* qr  = (ushort*)(ws);                 // [0,8M)
  ushort* kr  = (ushort*)(ws + BF);            // [8M,16M)
  ushort* vr  = (ushort*)(ws + 2 * BF);        // [16M,24M); Obf overlays after V-GEMM
  ushort* Obf = (ushort*)(ws + 2 * BF);
  ushort* Qbf = (ushort*)(ws + 3 * BF);        // [24M,32M)
  ushort* Kbf = (ushort*)(ws + 4 * BF);        // [32M,40M)
  ushort* Vt  = (ushort*)(ws + 5 * BF);        // [40M,48M)
  unsigned long long* mbits = (unsigned long long*)(ws + 6 * BF);      // 1 MiB
  ushort* Wqt = (ushort*)(ws + 6 * BF + (1 << 20));                    // 512 KiB
  ushort* Wvt = Wqt + 512 * 512;
  ushort* Wot = Wvt + 512 * 512;
  float*  X   = (float*)ws;                    // overlays qr+kr (dead after attn)

  const dim3 tb(256);

  prep_kern<<<dim3(2048, 4), tb, 0, stream>>>(q_in, k_in, v_in, smask,
                                              qr, kr, vr, mbits);
  wtrans3_kern<<<dim3(8, 8, 3), tb, 0, stream>>>(Wq, Wv, Wo, Wqt, Wvt, Wot);

  gemm_qkv_kern<<<dim3(64, 8, 3), tb, 0, stream>>>(qr, kr, vr, Wqt, Wvt,
                                                   bq, bv, Qbf, Kbf, Vt);

  attn_kern<<<dim3(64, 8), tb, 0, stream>>>(Qbf, Kbf, Vt, qr, kr, mbits,
                                            gammas, Obf);

  gemm_out_kern<<<dim3(64, 8), tb, 0, stream>>>(Obf, Wot, bo, q_in, X);
  ln_kern<<<2048, tb, 0, stream>>>(X, ln_g, ln_b, out);
}